// Round 4
// baseline (4584.740 us; speedup 1.0000x reference)
//
#include <hip/hip_runtime.h>
#include <math.h>

#define H    256
#define G4H  1024
#define CIN  512
#define BB   16
#define TT   2048
#define CHUNK 128
#define NPH  16   // TT/CHUNK

typedef unsigned long long ull;

// ---- workspace layout (in floats) ----
#define OFF_WQ      ((size_t)0)                        // 524288
#define OFF_PF0     ((size_t)524288)                   // 2097152 (proj fwd, parity 0)
#define OFF_PF1     ((size_t)2621440)                  // 2097152 (proj fwd, parity 1)
#define OFF_PB0     ((size_t)4718592)                  // 2097152 (proj bwd, parity 0)
#define OFF_PB1     ((size_t)6815744)                  // 2097152 (proj bwd, parity 1)
#define OFF_HBUF    ((size_t)8912896)                  // 16777216
#define OFF_STATS   ((size_t)25690112)                 // 1024
#define OFF_CSTATE  ((size_t)25691136)                 // 8192
#define OFF_HX      ((size_t)25699328)                 // 16384 ull = 32768 floats
#define OFF_W2      ((size_t)25732096)                 // 1024
#define OFF_B2      ((size_t)25733120)                 // 16
#define OFF_SAMP    ((size_t)25733136)                 // 32768
#define OFF_HLAST   ((size_t)25765904)                 // 8192 (cross-dispatch handoff)

#define REP16(X) X(0) X(1) X(2) X(3) X(4) X(5) X(6) X(7) X(8) X(9) X(10) X(11) \
  X(12) X(13) X(14) X(15)

// fast transcendentals for the LSTM cell (v_exp_f32 / v_rcp_f32 based; verified r1).
__device__ __forceinline__ float frcp_(float x) { return __builtin_amdgcn_rcpf(x); }
__device__ __forceinline__ float fsig_(float x) { return frcp_(1.f + __expf(-x)); }
__device__ __forceinline__ float ftanh_(float x) {
  float a = fabsf(x);
  float e = __expf(-2.f * a);
  float t = (1.f - e) * frcp_(1.f + e);
  return copysignf(t, x);
}

// ---------------- K0: repack Whh; zero stats + hx tag words ----------------
// wq float4 idx = (dir*4+kq)*16384 + q*1024 + gate*256 + s*32 + jl
__global__ __launch_bounds__(256) void k0_init(
    const float* __restrict__ WhhF, const float* __restrict__ WhhB,
    float4* __restrict__ wq, float* __restrict__ stats, int* __restrict__ hxw) {
  int idx = blockIdx.x * 256 + threadIdx.x;
  if (idx < 131072) {
    int jl = idx & 31, s = (idx >> 5) & 7, gate = (idx >> 8) & 3;
    int q = (idx >> 10) & 15, kq = (idx >> 14) & 3, dir = idx >> 16;
    int row = gate * 256 + s * 32 + jl;
    int col = kq * 64 + q * 4;
    const float* W = (dir ? WhhB : WhhF) + (size_t)row * H + col;
    wq[idx] = make_float4(W[0], W[1], W[2], W[3]);
  }
  if (idx < 1024) stats[idx] = 0.f;
  if (idx < 32768) hxw[idx] = 0;   // tags=0 < any target>=1
}

// ---------------- K12: fused tick-tock recurrence + next-phase proj GEMM ----
// k2 role (blocks < nk2=128): each WG serves BOTH chains of batch b (fwd=gA,
//   bwd=gB), 8 sibling WGs per b. Phases alternate A,B each step; the exchange
//   RT of one chain hides under the other's compute (self-staggering; worst
//   case degenerates to r3's per-chain cost). Exchange = r1's proven tagged
//   agent-atomic scheme, own slice via LDS, step-0 handoff via plain hlast.
// k1 role: 64t x 128g tile per block, 512 thr; writes proj for phase p1 into
//   the parity buffer k2 is NOT reading this dispatch.
__global__ __launch_bounds__(512, 1) void k12(
    const float4* __restrict__ wq,
    const float* __restrict__ pF2, const float* __restrict__ pB2,   // k2 reads
    float* __restrict__ pF1, float* __restrict__ pB1,               // k1 writes
    const float* __restrict__ x,
    const float* __restrict__ WihF, const float* __restrict__ bihF, const float* __restrict__ bhhF,
    const float* __restrict__ WihB, const float* __restrict__ bihB, const float* __restrict__ bhhB,
    float* __restrict__ hbuf, ull* __restrict__ hx2, float* __restrict__ hlast,
    float* __restrict__ cstate, float* __restrict__ stats,
    int nk2, int t0f2, int t0b2, int first, int ebase, int p1) {
  __shared__ __align__(16) float smem[16 * 68 + 16 * 132];  // 3200 floats, role-overlaid

  if ((int)blockIdx.x < nk2) {
    // ================= k2 role: paired LSTM recurrence =================
    float* h_ldsA = smem;          // [256]
    float* h_ldsB = smem + 256;    // [256]
    float* pbuf   = smem + 512;    // [512]
    const int tid = threadIdx.x;
    const int l = tid & 63, w = tid >> 6;
    const int jl = tid & 31, gate = (tid >> 5) & 3, kq = tid >> 7;
    const int bx = blockIdx.x;
    const int b = bx & 15, s = bx >> 4;     // 128 WGs: 16 b x 8 siblings
    const int gA = b, gB = 16 + b;          // chain ids (dir0, dir1)
    const int row = gate * 256 + s * 32 + jl;

    const float4* wbA = wq + (size_t)(kq) * 16384 + gate * 256 + s * 32 + jl;
    const float4* wbB = wq + (size_t)(4 + kq) * 16384 + gate * 256 + s * 32 + jl;
#define WDECLA(i) float ax##i, ay##i, az##i, aw##i; \
    { float4 t_ = wbA[(size_t)(i) * 1024]; \
      ax##i = t_.x; ay##i = t_.y; az##i = t_.z; aw##i = t_.w; } \
    asm volatile("" : "+v"(ax##i), "+v"(ay##i), "+v"(az##i), "+v"(aw##i));
    REP16(WDECLA)
#undef WDECLA
#define WDECLB(i) float bx##i, by##i, bz##i, bw##i; \
    { float4 t_ = wbB[(size_t)(i) * 1024]; \
      bx##i = t_.x; by##i = t_.y; bz##i = t_.z; bw##i = t_.w; } \
    asm volatile("" : "+v"(bx##i), "+v"(by##i), "+v"(bz##i), "+v"(bw##i));
    REP16(WDECLB)
#undef WDECLB

    float cA = 0.f, cB = 0.f, s1A = 0.f, s2A = 0.f, s1B = 0.f, s2B = 0.f;
    if (w == 0 && l < 32 && !first) {
      cA = cstate[gA * 256 + s * 32 + l];
      cB = cstate[gB * 256 + s * 32 + l];
    }

    float pvA = 0.f, pvB = 0.f;
    if (kq == 0) {
      pvA = pF2[((size_t)0 * BB + b) * G4H + row];
      pvB = pB2[((size_t)(CHUNK - 1) * BB + b) * G4H + row];
    }

    for (int step = 0; step < CHUNK; ++step) {
      int abs = ebase + step;

      // ======== phase A (fwd chain) ========
      if (tid < 256) {
        if (abs == 0) {
          h_ldsA[tid] = 0.f;
        } else if (step == 0) {
          h_ldsA[tid] = hlast[gA * 256 + tid];   // prev dispatch (stream-ordered)
        } else if ((tid >> 5) != s) {            // own slice already in h_ldsA
          ull* src = hx2 + (size_t)((abs - 1) & 1) * 8192 + gA * 256 + tid;
          ull wd = __hip_atomic_load(src, __ATOMIC_RELAXED, __HIP_MEMORY_SCOPE_AGENT);
          while ((int)(wd >> 32) < abs)
            wd = __hip_atomic_load(src, __ATOMIC_RELAXED, __HIP_MEMORY_SCOPE_AGENT);
          h_ldsA[tid] = __uint_as_float((unsigned)wd);
        }
      }
      __syncthreads();                          // A1: hA ready, pbuf free (prev B done)

      float acc = (kq == 0) ? pvA : 0.f;
      {
        const float4* h4p = ((const float4*)h_ldsA) + (kq << 4);
#define WFMA(i) { float4 hv = h4p[i]; \
        acc += ax##i * hv.x + ay##i * hv.y + az##i * hv.z + aw##i * hv.w; }
        REP16(WFMA)
#undef WFMA
      }
      pbuf[tid] = acc;
      __syncthreads();                          // A2: partials ready

      if (w == 0 && l < 32) {
        float gi = pbuf[l]       + pbuf[128 + l] + pbuf[256 + l] + pbuf[384 + l];
        float gf = pbuf[32 + l]  + pbuf[160 + l] + pbuf[288 + l] + pbuf[416 + l];
        float gg = pbuf[64 + l]  + pbuf[192 + l] + pbuf[320 + l] + pbuf[448 + l];
        float go = pbuf[96 + l]  + pbuf[224 + l] + pbuf[352 + l] + pbuf[480 + l];
        float ig = fsig_(gi), fg = fsig_(gf), gz = ftanh_(gg), og = fsig_(go);
        cA = fg * cA + ig * gz;
        float h = og * ftanh_(cA);
        s1A += h; s2A += h * h;
        int j = s * 32 + l;
        h_ldsA[j] = h;                          // own-slice local publish
        ull wd = ((ull)(unsigned)(abs + 1) << 32) | (ull)__float_as_uint(h);
        __hip_atomic_store(hx2 + (size_t)(abs & 1) * 8192 + gA * 256 + j, wd,
                           __ATOMIC_RELAXED, __HIP_MEMORY_SCOPE_AGENT);
        if (step == CHUNK - 1) hlast[gA * 256 + j] = h;
        int t = t0f2 + step;
        hbuf[((size_t)t * BB + b) * 512 + j] = h;
      }
      if (kq == 0 && step + 1 < CHUNK)
        pvA = pF2[((size_t)(step + 1) * BB + b) * G4H + row];

      // ======== phase B (bwd chain) ========
      if (tid < 256) {
        if (abs == 0) {
          h_ldsB[tid] = 0.f;
        } else if (step == 0) {
          h_ldsB[tid] = hlast[gB * 256 + tid];
        } else if ((tid >> 5) != s) {
          ull* src = hx2 + (size_t)((abs - 1) & 1) * 8192 + gB * 256 + tid;
          ull wd = __hip_atomic_load(src, __ATOMIC_RELAXED, __HIP_MEMORY_SCOPE_AGENT);
          while ((int)(wd >> 32) < abs)
            wd = __hip_atomic_load(src, __ATOMIC_RELAXED, __HIP_MEMORY_SCOPE_AGENT);
          h_ldsB[tid] = __uint_as_float((unsigned)wd);
        }
      }
      __syncthreads();                          // B1: hB ready, pbuf free (cell A done)

      acc = (kq == 0) ? pvB : 0.f;
      {
        const float4* h4p = ((const float4*)h_ldsB) + (kq << 4);
#define WFMA(i) { float4 hv = h4p[i]; \
        acc += bx##i * hv.x + by##i * hv.y + bz##i * hv.z + bw##i * hv.w; }
        REP16(WFMA)
#undef WFMA
      }
      pbuf[tid] = acc;
      __syncthreads();                          // B2: partials ready

      if (w == 0 && l < 32) {
        float gi = pbuf[l]       + pbuf[128 + l] + pbuf[256 + l] + pbuf[384 + l];
        float gf = pbuf[32 + l]  + pbuf[160 + l] + pbuf[288 + l] + pbuf[416 + l];
        float gg = pbuf[64 + l]  + pbuf[192 + l] + pbuf[320 + l] + pbuf[448 + l];
        float go = pbuf[96 + l]  + pbuf[224 + l] + pbuf[352 + l] + pbuf[480 + l];
        float ig = fsig_(gi), fg = fsig_(gf), gz = ftanh_(gg), og = fsig_(go);
        cB = fg * cB + ig * gz;
        float h = og * ftanh_(cB);
        s1B += h; s2B += h * h;
        int j = s * 32 + l;
        h_ldsB[j] = h;
        ull wd = ((ull)(unsigned)(abs + 1) << 32) | (ull)__float_as_uint(h);
        __hip_atomic_store(hx2 + (size_t)(abs & 1) * 8192 + gB * 256 + j, wd,
                           __ATOMIC_RELAXED, __HIP_MEMORY_SCOPE_AGENT);
        if (step == CHUNK - 1) hlast[gB * 256 + j] = h;
        int t = t0b2 + (CHUNK - 1 - step);
        hbuf[((size_t)t * BB + b) * 512 + 256 + j] = h;
      }
      if (kq == 0 && step + 1 < CHUNK)
        pvB = pB2[((size_t)(CHUNK - 2 - step) * BB + b) * G4H + row];
      // no bottom barrier: next phase-A poll + barrier A1 separates steps
    }

    if (w == 0 && l < 32) {
      cstate[gA * 256 + s * 32 + l] = cA;
      cstate[gB * 256 + s * 32 + l] = cB;
      atomicAdd(&stats[s * 32 + l], s1A);
      atomicAdd(&stats[512 + s * 32 + l], s2A);
      atomicAdd(&stats[256 + s * 32 + l], s1B);
      atomicAdd(&stats[768 + s * 32 + l], s2B);
    }
    return;
  }

  // ================= k1 role: proj GEMM for phase p1 =================
  if (p1 < 0) return;
  float* Xs = smem;             // [16][68]
  float* Ws = smem + 16 * 68;   // [16][132]
  int bid = (int)blockIdx.x - nk2;
  int ttile = bid & 1, gtile = (bid >> 1) & 7, zb = bid >> 4;
  int b = zb & 15, dir = zb >> 4;
  const float* Wih = dir ? WihB : WihF;
  const float* bih = dir ? bihB : bihF;
  const float* bhh = dir ? bhhB : bhhF;
  float* proj = dir ? pB1 : pF1;
  int t0 = (dir ? (NPH - 1 - p1) : p1) * CHUNK;
  int tbase = t0 + ttile * 64;
  int gbase = gtile * 128;
  int tid = threadIdx.x;
  int tx = tid & 15, ty = tid >> 4;           // ty 0..31
  float acc[4][4];
#pragma unroll
  for (int i = 0; i < 4; i++)
#pragma unroll
    for (int j = 0; j < 4; j++) acc[i][j] = 0.f;

  int lt = tid & 63, lk = tid >> 6;           // X: 2 rows (lk, lk+8) x 64 t
  int wg = tid >> 2, wc = tid & 3;            // W: 128 g-rows x one float4 of c
  const float* xb = x + (size_t)b * CIN * TT + tbase + lt;
  const float* wp = Wih + (size_t)(gbase + wg) * CIN + 4 * wc;

  float rxa = xb[(size_t)lk * TT];
  float rxb = xb[(size_t)(lk + 8) * TT];
  float4 rw = *(const float4*)wp;

  for (int c0 = 0; c0 < CIN; c0 += 16) {
    __syncthreads();
    Xs[lk * 68 + lt] = rxa;
    Xs[(lk + 8) * 68 + lt] = rxb;
    Ws[(4 * wc + 0) * 132 + wg] = rw.x;
    Ws[(4 * wc + 1) * 132 + wg] = rw.y;
    Ws[(4 * wc + 2) * 132 + wg] = rw.z;
    Ws[(4 * wc + 3) * 132 + wg] = rw.w;
    __syncthreads();
    if (c0 + 16 < CIN) {
      rxa = xb[(size_t)(c0 + 16 + lk) * TT];
      rxb = xb[(size_t)(c0 + 16 + lk + 8) * TT];
      rw  = *(const float4*)(wp + c0 + 16);
    }
#pragma unroll
    for (int kk = 0; kk < 16; kk++) {
      float4 av = *(const float4*)&Xs[kk * 68 + tx * 4];
      float4 bv = *(const float4*)&Ws[kk * 132 + ty * 4];
      acc[0][0] += av.x * bv.x; acc[0][1] += av.x * bv.y; acc[0][2] += av.x * bv.z; acc[0][3] += av.x * bv.w;
      acc[1][0] += av.y * bv.x; acc[1][1] += av.y * bv.y; acc[1][2] += av.y * bv.z; acc[1][3] += av.y * bv.w;
      acc[2][0] += av.z * bv.x; acc[2][1] += av.z * bv.y; acc[2][2] += av.z * bv.z; acc[2][3] += av.z * bv.w;
      acc[3][0] += av.w * bv.x; acc[3][1] += av.w * bv.y; acc[3][2] += av.w * bv.z; acc[3][3] += av.w * bv.w;
    }
  }
  int g0 = gbase + ty * 4;
  float bias0 = bih[g0 + 0] + bhh[g0 + 0];
  float bias1 = bih[g0 + 1] + bhh[g0 + 1];
  float bias2 = bih[g0 + 2] + bhh[g0 + 2];
  float bias3 = bih[g0 + 3] + bhh[g0 + 3];
#pragma unroll
  for (int i = 0; i < 4; i++) {
    int tc = ttile * 64 + tx * 4 + i;
    float4 st = make_float4(acc[i][0] + bias0, acc[i][1] + bias1,
                            acc[i][2] + bias2, acc[i][3] + bias3);
    *(float4*)(proj + ((size_t)tc * BB + b) * G4H + g0) = st;
  }
}

// ---------------- K3: fold BN into linear ----------------
__global__ __launch_bounds__(512) void k3_prep(
    const float* __restrict__ stats, const float* __restrict__ gamma,
    const float* __restrict__ beta, const float* __restrict__ Wlin,
    const float* __restrict__ blin, float* __restrict__ w2, float* __restrict__ b2) {
  __shared__ float r0[512], r1[512];
  int ch = threadIdx.x;
  float mean = stats[ch] * (1.f / 32768.f);
  float var  = stats[512 + ch] * (1.f / 32768.f) - mean * mean;
  float sc = gamma[ch] * rsqrtf(var + 1e-5f);
  float w0 = Wlin[ch], w1 = Wlin[512 + ch];
  w2[ch] = w0 * sc; w2[512 + ch] = w1 * sc;
  float tt = beta[ch] - mean * sc;
  r0[ch] = w0 * tt; r1[ch] = w1 * tt;
  __syncthreads();
  for (int off = 256; off > 0; off >>= 1) {
    if (ch < off) { r0[ch] += r0[ch + off]; r1[ch] += r1[ch + off]; }
    __syncthreads();
  }
  if (ch == 0) { b2[0] = blin[0] + r0[0]; b2[1] = blin[1] + r1[0]; }
}

// ---------------- K4: posterior + gumbel hard sample; one wave per (b,t) ----------------
__global__ __launch_bounds__(256) void k4_post(
    const float* __restrict__ hbuf, const float* __restrict__ w2,
    const float* __restrict__ b2, const float* __restrict__ u,
    const float* __restrict__ e, float* __restrict__ post,
    float* __restrict__ samp) {
  int wid = (blockIdx.x * 256 + threadIdx.x) >> 6;
  int lane = threadIdx.x & 63;
  int b = wid >> 11, t = wid & 2047;
  const float* hr = hbuf + ((size_t)t * BB + b) * 512;
  int c0 = lane * 8;
  float4 h0 = *(const float4*)(hr + c0);
  float4 h1 = *(const float4*)(hr + c0 + 4);
  float4 wa = *(const float4*)(w2 + c0);
  float4 wb = *(const float4*)(w2 + c0 + 4);
  float4 va = *(const float4*)(w2 + 512 + c0);
  float4 vb = *(const float4*)(w2 + 512 + c0 + 4);
  float d0 = h0.x * wa.x + h0.y * wa.y + h0.z * wa.z + h0.w * wa.w
           + h1.x * wb.x + h1.y * wb.y + h1.z * wb.z + h1.w * wb.w;
  float d1 = h0.x * va.x + h0.y * va.y + h0.z * va.z + h0.w * va.w
           + h1.x * vb.x + h1.y * vb.y + h1.z * vb.z + h1.w * vb.w;
#pragma unroll
  for (int off = 32; off > 0; off >>= 1) {
    d0 += __shfl_xor(d0, off, 64);
    d1 += __shfl_xor(d1, off, 64);
  }
  if (lane == 0) {
    float z0 = (d0 + b2[0]) * 0.1f, z1 = (d1 + b2[1]) * 0.1f;
    float m = fmaxf(z0, z1);
    float e0 = expf(z0 - m), e1 = expf(z1 - m);
    float inv = 1.f / (e0 + e1);
    float p0 = e0 * inv, p1 = e1 * inv;
    size_t o = (size_t)b * TT + t;
    post[o * 2] = p0; post[o * 2 + 1] = p1;
    float u0 = u[o * 2], u1 = u[o * 2 + 1];
    float g0 = -logf(-logf(u0 + 1e-20f) + 1e-20f);
    float g1 = -logf(-logf(u1 + 1e-20f) + 1e-20f);
    float a0 = logf(p0) + g0, a1 = logf(p1) + g1;
    samp[o] = (a1 > a0) ? e[o] : 0.f;  // strict >: np.argmax tie -> class 0
  }
}

// ---------------- K5: 3x median-of-5 (reflect pad), one WG per b ----------------
#define MSWAP(a, b) { float lo_ = fminf(a, b); b = fmaxf(a, b); a = lo_; }
__global__ __launch_bounds__(256) void k5_median(
    const float* __restrict__ samp, float* __restrict__ mask) {
  __shared__ float buf[2][TT];
  int b = blockIdx.x, tid = threadIdx.x;
  for (int i = tid; i < TT; i += 256) buf[0][i] = samp[(size_t)b * TT + i];
  __syncthreads();
  int src = 0;
  for (int pass = 0; pass < 3; ++pass) {
    for (int i = tid; i < TT; i += 256) {
      float v0, v1, v2, v3, v4;
      {
        int i0 = i - 2; i0 = i0 < 0 ? -i0 : i0;
        int i1 = i - 1; i1 = i1 < 0 ? -i1 : i1;
        int i3 = i + 1; i3 = i3 > TT - 1 ? 2 * (TT - 1) - i3 : i3;
        int i4 = i + 2; i4 = i4 > TT - 1 ? 2 * (TT - 1) - i4 : i4;
        v0 = buf[src][i0]; v1 = buf[src][i1]; v2 = buf[src][i];
        v3 = buf[src][i3]; v4 = buf[src][i4];
      }
      MSWAP(v0, v1); MSWAP(v3, v4); MSWAP(v2, v4); MSWAP(v2, v3);
      MSWAP(v1, v4); MSWAP(v0, v3); MSWAP(v0, v2); MSWAP(v1, v3);
      MSWAP(v1, v2);
      buf[1 - src][i] = v2;
    }
    __syncthreads();
    src = 1 - src;
  }
  for (int i = tid; i < TT; i += 256) mask[(size_t)b * TT + i] = buf[src][i];
}

extern "C" void kernel_launch(void* const* d_in, const int* in_sizes, int n_in,
                              void* d_out, int out_size, void* d_ws, size_t ws_size,
                              hipStream_t stream) {
  const float* x    = (const float*)d_in[0];
  const float* e    = (const float*)d_in[1];
  const float* u    = (const float*)d_in[2];
  const float* WihF = (const float*)d_in[3];
  const float* WhhF = (const float*)d_in[4];
  const float* bihF = (const float*)d_in[5];
  const float* bhhF = (const float*)d_in[6];
  const float* WihB = (const float*)d_in[7];
  const float* WhhB = (const float*)d_in[8];
  const float* bihB = (const float*)d_in[9];
  const float* bhhB = (const float*)d_in[10];
  const float* gamma= (const float*)d_in[11];
  const float* beta = (const float*)d_in[12];
  const float* Wlin = (const float*)d_in[13];
  const float* blin = (const float*)d_in[14];

  float* ws = (float*)d_ws;
  float4* wq    = (float4*)(ws + OFF_WQ);
  float* pf[2]  = { ws + OFF_PF0, ws + OFF_PF1 };
  float* pb[2]  = { ws + OFF_PB0, ws + OFF_PB1 };
  float* hbuf   = ws + OFF_HBUF;
  float* stats  = ws + OFF_STATS;
  float* cstate = ws + OFF_CSTATE;
  ull*   hx2    = (ull*)(ws + OFF_HX);
  float* w2     = ws + OFF_W2;
  float* b2     = ws + OFF_B2;
  float* samp   = ws + OFF_SAMP;
  float* hlast  = ws + OFF_HLAST;

  float* post = (float*)d_out;
  float* mask = (float*)d_out + (size_t)BB * TT * 2;

  hipLaunchKernelGGL(k0_init, dim3(512), dim3(256), 0, stream,
                     WhhF, WhhB, wq, stats, (int*)hx2);
  // prologue: proj for phase 0 into parity-0 buffers (k1 role only)
  hipLaunchKernelGGL(k12, dim3(512), dim3(512), 0, stream,
                     wq, pf[0], pb[0], pf[0], pb[0], x,
                     WihF, bihF, bhhF, WihB, bihB, bhhB,
                     hbuf, hx2, hlast, cstate, stats,
                     0, 0, 0, 1, 0, 0);
  for (int p = 0; p < NPH; ++p) {
    int q = p & 1;
    int np1 = (p + 1 < NPH) ? (p + 1) : -1;
    int nblk = 128 + ((np1 >= 0) ? 512 : 0);
    hipLaunchKernelGGL(k12, dim3(nblk), dim3(512), 0, stream,
                       wq, pf[q], pb[q], pf[q ^ 1], pb[q ^ 1], x,
                       WihF, bihF, bhhF, WihB, bihB, bhhB,
                       hbuf, hx2, hlast, cstate, stats,
                       128, p * CHUNK, (NPH - 1 - p) * CHUNK,
                       p == 0 ? 1 : 0, p * CHUNK, np1);
  }
  hipLaunchKernelGGL(k3_prep, dim3(1), dim3(512), 0, stream,
                     stats, gamma, beta, Wlin, blin, w2, b2);
  hipLaunchKernelGGL(k4_post, dim3(8192), dim3(256), 0, stream,
                     hbuf, w2, b2, u, e, post, samp);
  hipLaunchKernelGGL(k5_median, dim3(16), dim3(256), 0, stream, samp, mask);
}

// Round 5
// 4210.364 us; speedup vs baseline: 1.0889x; 1.0889x over previous
//
#include <hip/hip_runtime.h>
#include <math.h>

#define H    256
#define G4H  1024
#define CIN  512
#define BB   16
#define TT   2048
#define CHUNK 128
#define NPH  16   // TT/CHUNK

typedef unsigned long long ull;

// ---- workspace layout (in floats) ----
#define OFF_WQ      ((size_t)0)                        // 524288
#define OFF_PF0     ((size_t)524288)                   // 2097152 (proj fwd, parity 0)
#define OFF_PF1     ((size_t)2621440)                  // 2097152 (proj fwd, parity 1)
#define OFF_PB0     ((size_t)4718592)                  // 2097152 (proj bwd, parity 0)
#define OFF_PB1     ((size_t)6815744)                  // 2097152 (proj bwd, parity 1)
#define OFF_HBUF    ((size_t)8912896)                  // 16777216
#define OFF_STATS   ((size_t)25690112)                 // 1024
#define OFF_CSTATE  ((size_t)25691136)                 // 8192
#define OFF_HX      ((size_t)25699328)                 // 16384 ull = 32768 floats (slow/LLC)
#define OFF_W2      ((size_t)25732096)                 // 1024
#define OFF_B2      ((size_t)25733120)                 // 16
#define OFF_SAMP    ((size_t)25733136)                 // 32768
#define OFF_HLAST   ((size_t)25765904)                 // 8192 (cross-dispatch handoff)
#define OFF_HXF     ((size_t)25774096)                 // 16384 ull = 32768 floats (fast/L2)

#define REP16(X) X(0) X(1) X(2) X(3) X(4) X(5) X(6) X(7) X(8) X(9) X(10) X(11) \
  X(12) X(13) X(14) X(15)

// fast transcendentals for the LSTM cell (v_exp_f32 / v_rcp_f32 based; verified r1).
__device__ __forceinline__ float frcp_(float x) { return __builtin_amdgcn_rcpf(x); }
__device__ __forceinline__ float fsig_(float x) { return frcp_(1.f + __expf(-x)); }
__device__ __forceinline__ float ftanh_(float x) {
  float a = fabsf(x);
  float e = __expf(-2.f * a);
  float t = (1.f - e) * frcp_(1.f + e);
  return copysignf(t, x);
}

// SE-scope (L2-level) 8B load: bypasses L1, served by the XCD's shared L2.
__device__ __forceinline__ ull ld_sc0(const ull* p) {
  ull r;
  asm volatile("global_load_dwordx2 %0, %1, off sc0\n\ts_waitcnt vmcnt(0)"
               : "=v"(r) : "v"(p));
  return r;
}
// SE-scope (L2-level) 8B store: write-through to the XCD's shared L2.
__device__ __forceinline__ void st_sc0(ull* p, ull v) {
  asm volatile("global_store_dwordx2 %0, %1, off sc0"
               :: "v"(p), "v"(v) : "memory");
}

// ---------------- K0: repack Whh; zero stats + both exchange buffers ----------------
// wq float4 idx = (dir*4+kq)*16384 + q*1024 + gate*256 + s*32 + jl
__global__ __launch_bounds__(256) void k0_init(
    const float* __restrict__ WhhF, const float* __restrict__ WhhB,
    float4* __restrict__ wq, float* __restrict__ stats,
    int* __restrict__ hxw, int* __restrict__ hxfw) {
  int idx = blockIdx.x * 256 + threadIdx.x;
  if (idx < 131072) {
    int jl = idx & 31, s = (idx >> 5) & 7, gate = (idx >> 8) & 3;
    int q = (idx >> 10) & 15, kq = (idx >> 14) & 3, dir = idx >> 16;
    int row = gate * 256 + s * 32 + jl;
    int col = kq * 64 + q * 4;
    const float* W = (dir ? WhhB : WhhF) + (size_t)row * H + col;
    wq[idx] = make_float4(W[0], W[1], W[2], W[3]);
  }
  if (idx < 1024) stats[idx] = 0.f;
  if (idx < 32768) hxw[idx] = 0;    // slow tags=0 < any target>=1
  if (idx < 32768) hxfw[idx] = 0;   // fast tags=0
}

// ---------------- K12: fused recurrence (blocks < nk2) + next-phase proj GEMM ----
// k2 role: 8 sibling WGs x 512 thr per (dir,b); r1/r3's proven tagged agent-atomic
//   exchange PLUS an adaptive same-XCD L2 fast path:
//     publish: sc0 store to hxF (L2 write-through) first, then agent store to hx2.
//     acquire: capped sc0 poll of hxF; on cap-exhaust fall to the agent-scope spin,
//       then re-check hxF once -- if still absent while slow succeeded, the L2
//       rendezvous is broken for this pair -> disable fast permanently (per thread).
//   Own slice via LDS; step-0 handoff via plain hlast (stream-ordered).
// k1 role: 64t x 128g tile per block, 512 thr; writes proj for phase p1 into the
//   parity buffer k2 is NOT reading this dispatch.
__global__ __launch_bounds__(512, 1) void k12(
    const float4* __restrict__ wq,
    const float* __restrict__ pF2, const float* __restrict__ pB2,   // k2 reads
    float* __restrict__ pF1, float* __restrict__ pB1,               // k1 writes
    const float* __restrict__ x,
    const float* __restrict__ WihF, const float* __restrict__ bihF, const float* __restrict__ bhhF,
    const float* __restrict__ WihB, const float* __restrict__ bihB, const float* __restrict__ bhhB,
    float* __restrict__ hbuf, ull* __restrict__ hx2, ull* __restrict__ hxF,
    float* __restrict__ hlast, float* __restrict__ cstate, float* __restrict__ stats,
    int nk2, int t0f2, int t0b2, int first, int ebase, int p1) {
  __shared__ __align__(16) float smem[16 * 68 + 16 * 132];  // 3200 floats, role-overlaid

  if ((int)blockIdx.x < nk2) {
    // ================= k2 role: LSTM recurrence =================
    __builtin_amdgcn_s_setprio(1);   // favor recurrence waves over k1 GEMM waves
    float* h_lds = smem;          // [256]
    float* pbuf  = smem + 256;    // [512]
    const int tid = threadIdx.x;
    const int l = tid & 63, w = tid >> 6;
    const int jl = tid & 31, gate = (tid >> 5) & 3, kq = tid >> 7;
    const int bx = blockIdx.x;
    const int grp = bx & 31, s = bx >> 5;     // 8 siblings: {g, g+32, ..., g+224}
    const int dir = grp >> 4, b = grp & 15;
    const int row = gate * 256 + s * 32 + jl;

    const float4* wbase = wq + (size_t)(dir * 4 + kq) * 16384 + gate * 256 + s * 32 + jl;
#define WDECL(i) float wx##i, wy##i, wz##i, ww##i; \
    { float4 t_ = wbase[(size_t)(i) * 1024]; \
      wx##i = t_.x; wy##i = t_.y; wz##i = t_.z; ww##i = t_.w; } \
    asm volatile("" : "+v"(wx##i), "+v"(wy##i), "+v"(wz##i), "+v"(ww##i));
    REP16(WDECL)
#undef WDECL

    float c = 0.f, s1 = 0.f, s2 = 0.f;
    if (w == 0 && l < 32 && !first) c = cstate[grp * 256 + s * 32 + l];

    const float* pbase = dir ? pB2 : pF2;
    float pv = 0.f;
    if (kq == 0) {
      int tc0 = dir ? (CHUNK - 1) : 0;
      pv = pbase[((size_t)tc0 * BB + b) * G4H + row];
    }

    int fast_en = 1;   // per-thread adaptive L2-rendezvous flag

    for (int step = 0; step < CHUNK; ++step) {
      int abs = ebase + step;

      // acquire h_{abs-1}
      if (tid < 256) {
        if (abs == 0) {
          h_lds[tid] = 0.f;
        } else if (step == 0) {
          h_lds[tid] = hlast[grp * 256 + tid];   // prev dispatch (stream-ordered)
        } else if ((tid >> 5) != s) {            // own slice already in h_lds
          size_t off = (size_t)((abs - 1) & 1) * 8192 + grp * 256 + tid;
          ull wd = 0; int got = 0;
          if (fast_en) {
            const ull* pf_ = hxF + off;
            for (int tr = 0; tr < 64; ++tr) {
              wd = ld_sc0(pf_);
              if ((int)(wd >> 32) >= abs) { got = 1; break; }
            }
          }
          if (!got) {
            ull* src = hx2 + off;
            wd = __hip_atomic_load(src, __ATOMIC_RELAXED, __HIP_MEMORY_SCOPE_AGENT);
            while ((int)(wd >> 32) < abs)
              wd = __hip_atomic_load(src, __ATOMIC_RELAXED, __HIP_MEMORY_SCOPE_AGENT);
            if (fast_en) {
              // slow path delivered but fast never did -> mechanism broken here
              ull f = ld_sc0(hxF + off);
              if ((int)(f >> 32) < abs) fast_en = 0;
            }
          }
          h_lds[tid] = __uint_as_float((unsigned)wd);
        }
      }
      __syncthreads();                          // A: h ready

      float acc = (kq == 0) ? pv : 0.f;
      const float4* h4p = ((const float4*)h_lds) + (kq << 4);
#define WFMA(i) { float4 hv = h4p[i]; \
      acc += wx##i * hv.x + wy##i * hv.y + wz##i * hv.z + ww##i * hv.w; }
      REP16(WFMA)
#undef WFMA
      pbuf[tid] = acc;
      __syncthreads();                          // B: partials ready

      if (w == 0 && l < 32) {
        float gi = pbuf[l]       + pbuf[128 + l] + pbuf[256 + l] + pbuf[384 + l];
        float gf = pbuf[32 + l]  + pbuf[160 + l] + pbuf[288 + l] + pbuf[416 + l];
        float gg = pbuf[64 + l]  + pbuf[192 + l] + pbuf[320 + l] + pbuf[448 + l];
        float go = pbuf[96 + l]  + pbuf[224 + l] + pbuf[352 + l] + pbuf[480 + l];
        float ig = fsig_(gi);
        float fg = fsig_(gf);
        float gz = ftanh_(gg);
        float og = fsig_(go);
        c = fg * c + ig * gz;
        float h = og * ftanh_(c);
        s1 += h; s2 += h * h;
        int j = s * 32 + l;
        h_lds[j] = h;                           // own-slice local publish
        ull wd = ((ull)(unsigned)(abs + 1) << 32) | (ull)__float_as_uint(h);
        size_t off = (size_t)(abs & 1) * 8192 + grp * 256 + j;
        st_sc0(hxF + off, wd);                  // fast publish (XCD L2)
        __hip_atomic_store(hx2 + off, wd,
                           __ATOMIC_RELAXED, __HIP_MEMORY_SCOPE_AGENT);  // slow publish
        if (step == CHUNK - 1) hlast[grp * 256 + j] = h;  // next-dispatch handoff
        int tc = dir ? (CHUNK - 1 - step) : step;
        int t = (dir ? t0b2 : t0f2) + tc;
        hbuf[((size_t)t * BB + b) * 512 + dir * 256 + j] = h;
      }
      if (kq == 0 && step + 1 < CHUNK) {        // prefetch next proj
        int tcn = dir ? (CHUNK - 2 - step) : (step + 1);
        pv = pbase[((size_t)tcn * BB + b) * G4H + row];
      }
      // no bottom barrier: next poll + barrier A separates steps
    }

    if (w == 0 && l < 32) {
      cstate[grp * 256 + s * 32 + l] = c;
      atomicAdd(&stats[dir * 256 + s * 32 + l], s1);
      atomicAdd(&stats[512 + dir * 256 + s * 32 + l], s2);
    }
    return;
  }

  // ================= k1 role: proj GEMM for phase p1 =================
  if (p1 < 0) return;
  float* Xs = smem;             // [16][68]
  float* Ws = smem + 16 * 68;   // [16][132]
  int bid = (int)blockIdx.x - nk2;
  int ttile = bid & 1, gtile = (bid >> 1) & 7, zb = bid >> 4;
  int b = zb & 15, dir = zb >> 4;
  const float* Wih = dir ? WihB : WihF;
  const float* bih = dir ? bihB : bihF;
  const float* bhh = dir ? bhhB : bhhF;
  float* proj = dir ? pB1 : pF1;
  int t0 = (dir ? (NPH - 1 - p1) : p1) * CHUNK;
  int tbase = t0 + ttile * 64;
  int gbase = gtile * 128;
  int tid = threadIdx.x;
  int tx = tid & 15, ty = tid >> 4;           // ty 0..31
  float acc[4][4];
#pragma unroll
  for (int i = 0; i < 4; i++)
#pragma unroll
    for (int j = 0; j < 4; j++) acc[i][j] = 0.f;

  int lt = tid & 63, lk = tid >> 6;           // X: 2 rows (lk, lk+8) x 64 t
  int wg = tid >> 2, wc = tid & 3;            // W: 128 g-rows x one float4 of c
  const float* xb = x + (size_t)b * CIN * TT + tbase + lt;
  const float* wp = Wih + (size_t)(gbase + wg) * CIN + 4 * wc;

  float rxa = xb[(size_t)lk * TT];
  float rxb = xb[(size_t)(lk + 8) * TT];
  float4 rw = *(const float4*)wp;

  for (int c0 = 0; c0 < CIN; c0 += 16) {
    __syncthreads();
    Xs[lk * 68 + lt] = rxa;
    Xs[(lk + 8) * 68 + lt] = rxb;
    Ws[(4 * wc + 0) * 132 + wg] = rw.x;
    Ws[(4 * wc + 1) * 132 + wg] = rw.y;
    Ws[(4 * wc + 2) * 132 + wg] = rw.z;
    Ws[(4 * wc + 3) * 132 + wg] = rw.w;
    __syncthreads();
    if (c0 + 16 < CIN) {
      rxa = xb[(size_t)(c0 + 16 + lk) * TT];
      rxb = xb[(size_t)(c0 + 16 + lk + 8) * TT];
      rw  = *(const float4*)(wp + c0 + 16);
    }
#pragma unroll
    for (int kk = 0; kk < 16; kk++) {
      float4 av = *(const float4*)&Xs[kk * 68 + tx * 4];
      float4 bv = *(const float4*)&Ws[kk * 132 + ty * 4];
      acc[0][0] += av.x * bv.x; acc[0][1] += av.x * bv.y; acc[0][2] += av.x * bv.z; acc[0][3] += av.x * bv.w;
      acc[1][0] += av.y * bv.x; acc[1][1] += av.y * bv.y; acc[1][2] += av.y * bv.z; acc[1][3] += av.y * bv.w;
      acc[2][0] += av.z * bv.x; acc[2][1] += av.z * bv.y; acc[2][2] += av.z * bv.z; acc[2][3] += av.z * bv.w;
      acc[3][0] += av.w * bv.x; acc[3][1] += av.w * bv.y; acc[3][2] += av.w * bv.z; acc[3][3] += av.w * bv.w;
    }
  }
  int g0 = gbase + ty * 4;
  float bias0 = bih[g0 + 0] + bhh[g0 + 0];
  float bias1 = bih[g0 + 1] + bhh[g0 + 1];
  float bias2 = bih[g0 + 2] + bhh[g0 + 2];
  float bias3 = bih[g0 + 3] + bhh[g0 + 3];
#pragma unroll
  for (int i = 0; i < 4; i++) {
    int tc = ttile * 64 + tx * 4 + i;
    float4 st = make_float4(acc[i][0] + bias0, acc[i][1] + bias1,
                            acc[i][2] + bias2, acc[i][3] + bias3);
    *(float4*)(proj + ((size_t)tc * BB + b) * G4H + g0) = st;
  }
}

// ---------------- K3: fold BN into linear ----------------
__global__ __launch_bounds__(512) void k3_prep(
    const float* __restrict__ stats, const float* __restrict__ gamma,
    const float* __restrict__ beta, const float* __restrict__ Wlin,
    const float* __restrict__ blin, float* __restrict__ w2, float* __restrict__ b2) {
  __shared__ float r0[512], r1[512];
  int ch = threadIdx.x;
  float mean = stats[ch] * (1.f / 32768.f);
  float var  = stats[512 + ch] * (1.f / 32768.f) - mean * mean;
  float sc = gamma[ch] * rsqrtf(var + 1e-5f);
  float w0 = Wlin[ch], w1 = Wlin[512 + ch];
  w2[ch] = w0 * sc; w2[512 + ch] = w1 * sc;
  float tt = beta[ch] - mean * sc;
  r0[ch] = w0 * tt; r1[ch] = w1 * tt;
  __syncthreads();
  for (int off = 256; off > 0; off >>= 1) {
    if (ch < off) { r0[ch] += r0[ch + off]; r1[ch] += r1[ch + off]; }
    __syncthreads();
  }
  if (ch == 0) { b2[0] = blin[0] + r0[0]; b2[1] = blin[1] + r1[0]; }
}

// ---------------- K4: posterior + gumbel hard sample; one wave per (b,t) ----------------
__global__ __launch_bounds__(256) void k4_post(
    const float* __restrict__ hbuf, const float* __restrict__ w2,
    const float* __restrict__ b2, const float* __restrict__ u,
    const float* __restrict__ e, float* __restrict__ post,
    float* __restrict__ samp) {
  int wid = (blockIdx.x * 256 + threadIdx.x) >> 6;
  int lane = threadIdx.x & 63;
  int b = wid >> 11, t = wid & 2047;
  const float* hr = hbuf + ((size_t)t * BB + b) * 512;
  int c0 = lane * 8;
  float4 h0 = *(const float4*)(hr + c0);
  float4 h1 = *(const float4*)(hr + c0 + 4);
  float4 wa = *(const float4*)(w2 + c0);
  float4 wb = *(const float4*)(w2 + c0 + 4);
  float4 va = *(const float4*)(w2 + 512 + c0);
  float4 vb = *(const float4*)(w2 + 512 + c0 + 4);
  float d0 = h0.x * wa.x + h0.y * wa.y + h0.z * wa.z + h0.w * wa.w
           + h1.x * wb.x + h1.y * wb.y + h1.z * wb.z + h1.w * wb.w;
  float d1 = h0.x * va.x + h0.y * va.y + h0.z * va.z + h0.w * va.w
           + h1.x * vb.x + h1.y * vb.y + h1.z * vb.z + h1.w * vb.w;
#pragma unroll
  for (int off = 32; off > 0; off >>= 1) {
    d0 += __shfl_xor(d0, off, 64);
    d1 += __shfl_xor(d1, off, 64);
  }
  if (lane == 0) {
    float z0 = (d0 + b2[0]) * 0.1f, z1 = (d1 + b2[1]) * 0.1f;
    float m = fmaxf(z0, z1);
    float e0 = expf(z0 - m), e1 = expf(z1 - m);
    float inv = 1.f / (e0 + e1);
    float p0 = e0 * inv, p1 = e1 * inv;
    size_t o = (size_t)b * TT + t;
    post[o * 2] = p0; post[o * 2 + 1] = p1;
    float u0 = u[o * 2], u1 = u[o * 2 + 1];
    float g0 = -logf(-logf(u0 + 1e-20f) + 1e-20f);
    float g1 = -logf(-logf(u1 + 1e-20f) + 1e-20f);
    float a0 = logf(p0) + g0, a1 = logf(p1) + g1;
    samp[o] = (a1 > a0) ? e[o] : 0.f;  // strict >: np.argmax tie -> class 0
  }
}

// ---------------- K5: 3x median-of-5 (reflect pad), one WG per b ----------------
#define MSWAP(a, b) { float lo_ = fminf(a, b); b = fmaxf(a, b); a = lo_; }
__global__ __launch_bounds__(256) void k5_median(
    const float* __restrict__ samp, float* __restrict__ mask) {
  __shared__ float buf[2][TT];
  int b = blockIdx.x, tid = threadIdx.x;
  for (int i = tid; i < TT; i += 256) buf[0][i] = samp[(size_t)b * TT + i];
  __syncthreads();
  int src = 0;
  for (int pass = 0; pass < 3; ++pass) {
    for (int i = tid; i < TT; i += 256) {
      float v0, v1, v2, v3, v4;
      {
        int i0 = i - 2; i0 = i0 < 0 ? -i0 : i0;
        int i1 = i - 1; i1 = i1 < 0 ? -i1 : i1;
        int i3 = i + 1; i3 = i3 > TT - 1 ? 2 * (TT - 1) - i3 : i3;
        int i4 = i + 2; i4 = i4 > TT - 1 ? 2 * (TT - 1) - i4 : i4;
        v0 = buf[src][i0]; v1 = buf[src][i1]; v2 = buf[src][i];
        v3 = buf[src][i3]; v4 = buf[src][i4];
      }
      MSWAP(v0, v1); MSWAP(v3, v4); MSWAP(v2, v4); MSWAP(v2, v3);
      MSWAP(v1, v4); MSWAP(v0, v3); MSWAP(v0, v2); MSWAP(v1, v3);
      MSWAP(v1, v2);
      buf[1 - src][i] = v2;
    }
    __syncthreads();
    src = 1 - src;
  }
  for (int i = tid; i < TT; i += 256) mask[(size_t)b * TT + i] = buf[src][i];
}

extern "C" void kernel_launch(void* const* d_in, const int* in_sizes, int n_in,
                              void* d_out, int out_size, void* d_ws, size_t ws_size,
                              hipStream_t stream) {
  const float* x    = (const float*)d_in[0];
  const float* e    = (const float*)d_in[1];
  const float* u    = (const float*)d_in[2];
  const float* WihF = (const float*)d_in[3];
  const float* WhhF = (const float*)d_in[4];
  const float* bihF = (const float*)d_in[5];
  const float* bhhF = (const float*)d_in[6];
  const float* WihB = (const float*)d_in[7];
  const float* WhhB = (const float*)d_in[8];
  const float* bihB = (const float*)d_in[9];
  const float* bhhB = (const float*)d_in[10];
  const float* gamma= (const float*)d_in[11];
  const float* beta = (const float*)d_in[12];
  const float* Wlin = (const float*)d_in[13];
  const float* blin = (const float*)d_in[14];

  float* ws = (float*)d_ws;
  float4* wq    = (float4*)(ws + OFF_WQ);
  float* pf[2]  = { ws + OFF_PF0, ws + OFF_PF1 };
  float* pb[2]  = { ws + OFF_PB0, ws + OFF_PB1 };
  float* hbuf   = ws + OFF_HBUF;
  float* stats  = ws + OFF_STATS;
  float* cstate = ws + OFF_CSTATE;
  ull*   hx2    = (ull*)(ws + OFF_HX);
  float* w2     = ws + OFF_W2;
  float* b2     = ws + OFF_B2;
  float* samp   = ws + OFF_SAMP;
  float* hlast  = ws + OFF_HLAST;
  ull*   hxF    = (ull*)(ws + OFF_HXF);

  float* post = (float*)d_out;
  float* mask = (float*)d_out + (size_t)BB * TT * 2;

  hipLaunchKernelGGL(k0_init, dim3(512), dim3(256), 0, stream,
                     WhhF, WhhB, wq, stats, (int*)hx2, (int*)hxF);
  // prologue: proj for phase 0 into parity-0 buffers (k1 role only)
  hipLaunchKernelGGL(k12, dim3(512), dim3(512), 0, stream,
                     wq, pf[0], pb[0], pf[0], pb[0], x,
                     WihF, bihF, bhhF, WihB, bihB, bhhB,
                     hbuf, hx2, hxF, hlast, cstate, stats,
                     0, 0, 0, 1, 0, 0);
  for (int p = 0; p < NPH; ++p) {
    int q = p & 1;
    int np1 = (p + 1 < NPH) ? (p + 1) : -1;
    int nblk = 256 + ((np1 >= 0) ? 512 : 0);
    hipLaunchKernelGGL(k12, dim3(nblk), dim3(512), 0, stream,
                       wq, pf[q], pb[q], pf[q ^ 1], pb[q ^ 1], x,
                       WihF, bihF, bhhF, WihB, bihB, bhhB,
                       hbuf, hx2, hxF, hlast, cstate, stats,
                       256, p * CHUNK, (NPH - 1 - p) * CHUNK,
                       p == 0 ? 1 : 0, p * CHUNK, np1);
  }
  hipLaunchKernelGGL(k3_prep, dim3(1), dim3(512), 0, stream,
                     stats, gamma, beta, Wlin, blin, w2, b2);
  hipLaunchKernelGGL(k4_post, dim3(8192), dim3(256), 0, stream,
                     hbuf, w2, b2, u, e, post, samp);
  hipLaunchKernelGGL(k5_median, dim3(16), dim3(256), 0, stream, samp, mask);
}

// Round 6
// 3343.327 us; speedup vs baseline: 1.3713x; 1.2593x over previous
//
#include <hip/hip_runtime.h>
#include <math.h>

#define H    256
#define G4H  1024
#define CIN  512
#define BB   16
#define TT   2048
#define CHUNK 128
#define NPH  16   // TT/CHUNK

typedef unsigned long long ull;

// ---- workspace layout (in floats) ----
#define OFF_WQ      ((size_t)0)                        // 524288
#define OFF_PF0     ((size_t)524288)                   // 2097152 (proj fwd, parity 0)
#define OFF_PF1     ((size_t)2621440)                  // 2097152 (proj fwd, parity 1)
#define OFF_PB0     ((size_t)4718592)                  // 2097152 (proj bwd, parity 0)
#define OFF_PB1     ((size_t)6815744)                  // 2097152 (proj bwd, parity 1)
#define OFF_HBUF    ((size_t)8912896)                  // 16777216
#define OFF_STATS   ((size_t)25690112)                 // 1024
#define OFF_CSTATE  ((size_t)25691136)                 // 8192
#define OFF_HX      ((size_t)25699328)                 // 16384 ull = 32768 floats
#define OFF_W2      ((size_t)25732096)                 // 1024
#define OFF_B2      ((size_t)25733120)                 // 16
#define OFF_SAMP    ((size_t)25733136)                 // 32768
#define OFF_HLAST   ((size_t)25765904)                 // 8192 (cross-dispatch handoff)

#define REP16(X) X(0) X(1) X(2) X(3) X(4) X(5) X(6) X(7) X(8) X(9) X(10) X(11) \
  X(12) X(13) X(14) X(15)

// fast transcendentals for the LSTM cell (v_exp_f32 / v_rcp_f32 based; verified r1).
__device__ __forceinline__ float frcp_(float x) { return __builtin_amdgcn_rcpf(x); }
__device__ __forceinline__ float fsig_(float x) { return frcp_(1.f + __expf(-x)); }
__device__ __forceinline__ float ftanh_(float x) {
  float a = fabsf(x);
  float e = __expf(-2.f * a);
  float t = (1.f - e) * frcp_(1.f + e);
  return copysignf(t, x);
}

// ---------------- K0: repack Whh; zero stats + hx tag words ----------------
// wq float4 idx = (dir*4+kq)*16384 + q*1024 + gate*256 + s*32 + jl
__global__ __launch_bounds__(256) void k0_init(
    const float* __restrict__ WhhF, const float* __restrict__ WhhB,
    float4* __restrict__ wq, float* __restrict__ stats, int* __restrict__ hxw) {
  int idx = blockIdx.x * 256 + threadIdx.x;
  if (idx < 131072) {
    int jl = idx & 31, s = (idx >> 5) & 7, gate = (idx >> 8) & 3;
    int q = (idx >> 10) & 15, kq = (idx >> 14) & 3, dir = idx >> 16;
    int row = gate * 256 + s * 32 + jl;
    int col = kq * 64 + q * 4;
    const float* W = (dir ? WhhB : WhhF) + (size_t)row * H + col;
    wq[idx] = make_float4(W[0], W[1], W[2], W[3]);
  }
  if (idx < 1024) stats[idx] = 0.f;
  if (idx < 32768) hxw[idx] = 0;   // tags=0 < any target>=1
}

// ---------------- K12: fused recurrence (blocks < nk2) + next-phase proj GEMM ----
// k2 role: 8 sibling WGs x 512 thr per (dir,b); r1/r3's proven tagged agent-atomic
//   exchange. r6 deltas (exchange semantics unchanged):
//   - ping-pong double poll: two independent load chains to the same tagged word,
//     checked alternately -> LLC sampling period ~halves vs a serial poll loop.
//   - publish via 64b atomicExch (fire-and-forget RMW executes at the coherence
//     point; avoids store-buffer dwell), issued before s1/s2/hbuf bookkeeping.
//   Own slice via LDS; step-0 handoff via plain hlast (stream-ordered).
// k1 role: 64t x 128g tile per block, 512 thr; writes proj for phase p1 into the
//   parity buffer k2 is NOT reading this dispatch.
__global__ __launch_bounds__(512, 1) void k12(
    const float4* __restrict__ wq,
    const float* __restrict__ pF2, const float* __restrict__ pB2,   // k2 reads
    float* __restrict__ pF1, float* __restrict__ pB1,               // k1 writes
    const float* __restrict__ x,
    const float* __restrict__ WihF, const float* __restrict__ bihF, const float* __restrict__ bhhF,
    const float* __restrict__ WihB, const float* __restrict__ bihB, const float* __restrict__ bhhB,
    float* __restrict__ hbuf, ull* __restrict__ hx2, float* __restrict__ hlast,
    float* __restrict__ cstate, float* __restrict__ stats,
    int nk2, int t0f2, int t0b2, int first, int ebase, int p1) {
  __shared__ __align__(16) float smem[16 * 68 + 16 * 132];  // 3200 floats, role-overlaid

  if ((int)blockIdx.x < nk2) {
    // ================= k2 role: LSTM recurrence =================
    float* h_lds = smem;          // [256]
    float* pbuf  = smem + 256;    // [512]
    const int tid = threadIdx.x;
    const int l = tid & 63, w = tid >> 6;
    const int jl = tid & 31, gate = (tid >> 5) & 3, kq = tid >> 7;
    const int bx = blockIdx.x;
    const int grp = bx & 31, s = bx >> 5;     // 8 siblings: {g, g+32, ..., g+224}
    const int dir = grp >> 4, b = grp & 15;
    const int row = gate * 256 + s * 32 + jl;

    const float4* wbase = wq + (size_t)(dir * 4 + kq) * 16384 + gate * 256 + s * 32 + jl;
#define WDECL(i) float wx##i, wy##i, wz##i, ww##i; \
    { float4 t_ = wbase[(size_t)(i) * 1024]; \
      wx##i = t_.x; wy##i = t_.y; wz##i = t_.z; ww##i = t_.w; } \
    asm volatile("" : "+v"(wx##i), "+v"(wy##i), "+v"(wz##i), "+v"(ww##i));
    REP16(WDECL)
#undef WDECL

    float c = 0.f, s1 = 0.f, s2 = 0.f;
    if (w == 0 && l < 32 && !first) c = cstate[grp * 256 + s * 32 + l];

    const float* pbase = dir ? pB2 : pF2;
    float pv = 0.f;
    if (kq == 0) {
      int tc0 = dir ? (CHUNK - 1) : 0;
      pv = pbase[((size_t)tc0 * BB + b) * G4H + row];
    }

    for (int step = 0; step < CHUNK; ++step) {
      int abs = ebase + step;

      // acquire h_{abs-1}
      if (tid < 256) {
        if (abs == 0) {
          h_lds[tid] = 0.f;
        } else if (step == 0) {
          h_lds[tid] = hlast[grp * 256 + tid];   // prev dispatch (stream-ordered)
        } else if ((tid >> 5) != s) {            // own slice already in h_lds
          ull* src = hx2 + (size_t)((abs - 1) & 1) * 8192 + grp * 256 + tid;
          // ping-pong double poll: two in-flight sample chains, ~half the
          // serial-poll sampling period.
          ull wa = __hip_atomic_load(src, __ATOMIC_RELAXED, __HIP_MEMORY_SCOPE_AGENT);
          ull wb = __hip_atomic_load(src, __ATOMIC_RELAXED, __HIP_MEMORY_SCOPE_AGENT);
          ull wd;
          while (true) {
            if ((int)(wa >> 32) >= abs) { wd = wa; break; }
            wa = __hip_atomic_load(src, __ATOMIC_RELAXED, __HIP_MEMORY_SCOPE_AGENT);
            if ((int)(wb >> 32) >= abs) { wd = wb; break; }
            wb = __hip_atomic_load(src, __ATOMIC_RELAXED, __HIP_MEMORY_SCOPE_AGENT);
          }
          h_lds[tid] = __uint_as_float((unsigned)wd);
        }
      }
      __syncthreads();                          // A: h ready

      float acc = (kq == 0) ? pv : 0.f;
      const float4* h4p = ((const float4*)h_lds) + (kq << 4);
#define WFMA(i) { float4 hv = h4p[i]; \
      acc += wx##i * hv.x + wy##i * hv.y + wz##i * hv.z + ww##i * hv.w; }
      REP16(WFMA)
#undef WFMA
      pbuf[tid] = acc;
      __syncthreads();                          // B: partials ready

      if (w == 0 && l < 32) {
        float gi = pbuf[l]       + pbuf[128 + l] + pbuf[256 + l] + pbuf[384 + l];
        float gf = pbuf[32 + l]  + pbuf[160 + l] + pbuf[288 + l] + pbuf[416 + l];
        float gg = pbuf[64 + l]  + pbuf[192 + l] + pbuf[320 + l] + pbuf[448 + l];
        float go = pbuf[96 + l]  + pbuf[224 + l] + pbuf[352 + l] + pbuf[480 + l];
        float ig = fsig_(gi);
        float fg = fsig_(gf);
        float gz = ftanh_(gg);
        float og = fsig_(go);
        c = fg * c + ig * gz;
        float h = og * ftanh_(c);
        int j = s * 32 + l;
        // publish FIRST (critical path): RMW executes at the coherence point.
        ull wd = ((ull)(unsigned)(abs + 1) << 32) | (ull)__float_as_uint(h);
        atomicExch(hx2 + (size_t)(abs & 1) * 8192 + grp * 256 + j, wd);
        h_lds[j] = h;                           // own-slice local publish
        s1 += h; s2 += h * h;
        if (step == CHUNK - 1) hlast[grp * 256 + j] = h;  // next-dispatch handoff
        int tc = dir ? (CHUNK - 1 - step) : step;
        int t = (dir ? t0b2 : t0f2) + tc;
        hbuf[((size_t)t * BB + b) * 512 + dir * 256 + j] = h;
      }
      if (kq == 0 && step + 1 < CHUNK) {        // prefetch next proj
        int tcn = dir ? (CHUNK - 2 - step) : (step + 1);
        pv = pbase[((size_t)tcn * BB + b) * G4H + row];
      }
      // no bottom barrier: next poll + barrier A separates steps
    }

    if (w == 0 && l < 32) {
      cstate[grp * 256 + s * 32 + l] = c;
      atomicAdd(&stats[dir * 256 + s * 32 + l], s1);
      atomicAdd(&stats[512 + dir * 256 + s * 32 + l], s2);
    }
    return;
  }

  // ================= k1 role: proj GEMM for phase p1 =================
  if (p1 < 0) return;
  float* Xs = smem;             // [16][68]
  float* Ws = smem + 16 * 68;   // [16][132]
  int bid = (int)blockIdx.x - nk2;
  int ttile = bid & 1, gtile = (bid >> 1) & 7, zb = bid >> 4;
  int b = zb & 15, dir = zb >> 4;
  const float* Wih = dir ? WihB : WihF;
  const float* bih = dir ? bihB : bihF;
  const float* bhh = dir ? bhhB : bhhF;
  float* proj = dir ? pB1 : pF1;
  int t0 = (dir ? (NPH - 1 - p1) : p1) * CHUNK;
  int tbase = t0 + ttile * 64;
  int gbase = gtile * 128;
  int tid = threadIdx.x;
  int tx = tid & 15, ty = tid >> 4;           // ty 0..31
  float acc[4][4];
#pragma unroll
  for (int i = 0; i < 4; i++)
#pragma unroll
    for (int j = 0; j < 4; j++) acc[i][j] = 0.f;

  int lt = tid & 63, lk = tid >> 6;           // X: 2 rows (lk, lk+8) x 64 t
  int wg = tid >> 2, wc = tid & 3;            // W: 128 g-rows x one float4 of c
  const float* xb = x + (size_t)b * CIN * TT + tbase + lt;
  const float* wp = Wih + (size_t)(gbase + wg) * CIN + 4 * wc;

  float rxa = xb[(size_t)lk * TT];
  float rxb = xb[(size_t)(lk + 8) * TT];
  float4 rw = *(const float4*)wp;

  for (int c0 = 0; c0 < CIN; c0 += 16) {
    __syncthreads();
    Xs[lk * 68 + lt] = rxa;
    Xs[(lk + 8) * 68 + lt] = rxb;
    Ws[(4 * wc + 0) * 132 + wg] = rw.x;
    Ws[(4 * wc + 1) * 132 + wg] = rw.y;
    Ws[(4 * wc + 2) * 132 + wg] = rw.z;
    Ws[(4 * wc + 3) * 132 + wg] = rw.w;
    __syncthreads();
    if (c0 + 16 < CIN) {
      rxa = xb[(size_t)(c0 + 16 + lk) * TT];
      rxb = xb[(size_t)(c0 + 16 + lk + 8) * TT];
      rw  = *(const float4*)(wp + c0 + 16);
    }
#pragma unroll
    for (int kk = 0; kk < 16; kk++) {
      float4 av = *(const float4*)&Xs[kk * 68 + tx * 4];
      float4 bv = *(const float4*)&Ws[kk * 132 + ty * 4];
      acc[0][0] += av.x * bv.x; acc[0][1] += av.x * bv.y; acc[0][2] += av.x * bv.z; acc[0][3] += av.x * bv.w;
      acc[1][0] += av.y * bv.x; acc[1][1] += av.y * bv.y; acc[1][2] += av.y * bv.z; acc[1][3] += av.y * bv.w;
      acc[2][0] += av.z * bv.x; acc[2][1] += av.z * bv.y; acc[2][2] += av.z * bv.z; acc[2][3] += av.z * bv.w;
      acc[3][0] += av.w * bv.x; acc[3][1] += av.w * bv.y; acc[3][2] += av.w * bv.z; acc[3][3] += av.w * bv.w;
    }
  }
  int g0 = gbase + ty * 4;
  float bias0 = bih[g0 + 0] + bhh[g0 + 0];
  float bias1 = bih[g0 + 1] + bhh[g0 + 1];
  float bias2 = bih[g0 + 2] + bhh[g0 + 2];
  float bias3 = bih[g0 + 3] + bhh[g0 + 3];
#pragma unroll
  for (int i = 0; i < 4; i++) {
    int tc = ttile * 64 + tx * 4 + i;
    float4 st = make_float4(acc[i][0] + bias0, acc[i][1] + bias1,
                            acc[i][2] + bias2, acc[i][3] + bias3);
    *(float4*)(proj + ((size_t)tc * BB + b) * G4H + g0) = st;
  }
}

// ---------------- K3: fold BN into linear ----------------
__global__ __launch_bounds__(512) void k3_prep(
    const float* __restrict__ stats, const float* __restrict__ gamma,
    const float* __restrict__ beta, const float* __restrict__ Wlin,
    const float* __restrict__ blin, float* __restrict__ w2, float* __restrict__ b2) {
  __shared__ float r0[512], r1[512];
  int ch = threadIdx.x;
  float mean = stats[ch] * (1.f / 32768.f);
  float var  = stats[512 + ch] * (1.f / 32768.f) - mean * mean;
  float sc = gamma[ch] * rsqrtf(var + 1e-5f);
  float w0 = Wlin[ch], w1 = Wlin[512 + ch];
  w2[ch] = w0 * sc; w2[512 + ch] = w1 * sc;
  float tt = beta[ch] - mean * sc;
  r0[ch] = w0 * tt; r1[ch] = w1 * tt;
  __syncthreads();
  for (int off = 256; off > 0; off >>= 1) {
    if (ch < off) { r0[ch] += r0[ch + off]; r1[ch] += r1[ch + off]; }
    __syncthreads();
  }
  if (ch == 0) { b2[0] = blin[0] + r0[0]; b2[1] = blin[1] + r1[0]; }
}

// ---------------- K4: posterior + gumbel hard sample; one wave per (b,t) ----------------
__global__ __launch_bounds__(256) void k4_post(
    const float* __restrict__ hbuf, const float* __restrict__ w2,
    const float* __restrict__ b2, const float* __restrict__ u,
    const float* __restrict__ e, float* __restrict__ post,
    float* __restrict__ samp) {
  int wid = (blockIdx.x * 256 + threadIdx.x) >> 6;
  int lane = threadIdx.x & 63;
  int b = wid >> 11, t = wid & 2047;
  const float* hr = hbuf + ((size_t)t * BB + b) * 512;
  int c0 = lane * 8;
  float4 h0 = *(const float4*)(hr + c0);
  float4 h1 = *(const float4*)(hr + c0 + 4);
  float4 wa = *(const float4*)(w2 + c0);
  float4 wb = *(const float4*)(w2 + c0 + 4);
  float4 va = *(const float4*)(w2 + 512 + c0);
  float4 vb = *(const float4*)(w2 + 512 + c0 + 4);
  float d0 = h0.x * wa.x + h0.y * wa.y + h0.z * wa.z + h0.w * wa.w
           + h1.x * wb.x + h1.y * wb.y + h1.z * wb.z + h1.w * wb.w;
  float d1 = h0.x * va.x + h0.y * va.y + h0.z * va.z + h0.w * va.w
           + h1.x * vb.x + h1.y * vb.y + h1.z * vb.z + h1.w * vb.w;
#pragma unroll
  for (int off = 32; off > 0; off >>= 1) {
    d0 += __shfl_xor(d0, off, 64);
    d1 += __shfl_xor(d1, off, 64);
  }
  if (lane == 0) {
    float z0 = (d0 + b2[0]) * 0.1f, z1 = (d1 + b2[1]) * 0.1f;
    float m = fmaxf(z0, z1);
    float e0 = expf(z0 - m), e1 = expf(z1 - m);
    float inv = 1.f / (e0 + e1);
    float p0 = e0 * inv, p1 = e1 * inv;
    size_t o = (size_t)b * TT + t;
    post[o * 2] = p0; post[o * 2 + 1] = p1;
    float u0 = u[o * 2], u1 = u[o * 2 + 1];
    float g0 = -logf(-logf(u0 + 1e-20f) + 1e-20f);
    float g1 = -logf(-logf(u1 + 1e-20f) + 1e-20f);
    float a0 = logf(p0) + g0, a1 = logf(p1) + g1;
    samp[o] = (a1 > a0) ? e[o] : 0.f;  // strict >: np.argmax tie -> class 0
  }
}

// ---------------- K5: 3x median-of-5 (reflect pad), one WG per b ----------------
#define MSWAP(a, b) { float lo_ = fminf(a, b); b = fmaxf(a, b); a = lo_; }
__global__ __launch_bounds__(256) void k5_median(
    const float* __restrict__ samp, float* __restrict__ mask) {
  __shared__ float buf[2][TT];
  int b = blockIdx.x, tid = threadIdx.x;
  for (int i = tid; i < TT; i += 256) buf[0][i] = samp[(size_t)b * TT + i];
  __syncthreads();
  int src = 0;
  for (int pass = 0; pass < 3; ++pass) {
    for (int i = tid; i < TT; i += 256) {
      float v0, v1, v2, v3, v4;
      {
        int i0 = i - 2; i0 = i0 < 0 ? -i0 : i0;
        int i1 = i - 1; i1 = i1 < 0 ? -i1 : i1;
        int i3 = i + 1; i3 = i3 > TT - 1 ? 2 * (TT - 1) - i3 : i3;
        int i4 = i + 2; i4 = i4 > TT - 1 ? 2 * (TT - 1) - i4 : i4;
        v0 = buf[src][i0]; v1 = buf[src][i1]; v2 = buf[src][i];
        v3 = buf[src][i3]; v4 = buf[src][i4];
      }
      MSWAP(v0, v1); MSWAP(v3, v4); MSWAP(v2, v4); MSWAP(v2, v3);
      MSWAP(v1, v4); MSWAP(v0, v3); MSWAP(v0, v2); MSWAP(v1, v3);
      MSWAP(v1, v2);
      buf[1 - src][i] = v2;
    }
    __syncthreads();
    src = 1 - src;
  }
  for (int i = tid; i < TT; i += 256) mask[(size_t)b * TT + i] = buf[src][i];
}

extern "C" void kernel_launch(void* const* d_in, const int* in_sizes, int n_in,
                              void* d_out, int out_size, void* d_ws, size_t ws_size,
                              hipStream_t stream) {
  const float* x    = (const float*)d_in[0];
  const float* e    = (const float*)d_in[1];
  const float* u    = (const float*)d_in[2];
  const float* WihF = (const float*)d_in[3];
  const float* WhhF = (const float*)d_in[4];
  const float* bihF = (const float*)d_in[5];
  const float* bhhF = (const float*)d_in[6];
  const float* WihB = (const float*)d_in[7];
  const float* WhhB = (const float*)d_in[8];
  const float* bihB = (const float*)d_in[9];
  const float* bhhB = (const float*)d_in[10];
  const float* gamma= (const float*)d_in[11];
  const float* beta = (const float*)d_in[12];
  const float* Wlin = (const float*)d_in[13];
  const float* blin = (const float*)d_in[14];

  float* ws = (float*)d_ws;
  float4* wq    = (float4*)(ws + OFF_WQ);
  float* pf[2]  = { ws + OFF_PF0, ws + OFF_PF1 };
  float* pb[2]  = { ws + OFF_PB0, ws + OFF_PB1 };
  float* hbuf   = ws + OFF_HBUF;
  float* stats  = ws + OFF_STATS;
  float* cstate = ws + OFF_CSTATE;
  ull*   hx2    = (ull*)(ws + OFF_HX);
  float* w2     = ws + OFF_W2;
  float* b2     = ws + OFF_B2;
  float* samp   = ws + OFF_SAMP;
  float* hlast  = ws + OFF_HLAST;

  float* post = (float*)d_out;
  float* mask = (float*)d_out + (size_t)BB * TT * 2;

  hipLaunchKernelGGL(k0_init, dim3(512), dim3(256), 0, stream,
                     WhhF, WhhB, wq, stats, (int*)hx2);
  // prologue: proj for phase 0 into parity-0 buffers (k1 role only)
  hipLaunchKernelGGL(k12, dim3(512), dim3(512), 0, stream,
                     wq, pf[0], pb[0], pf[0], pb[0], x,
                     WihF, bihF, bhhF, WihB, bihB, bhhB,
                     hbuf, hx2, hlast, cstate, stats,
                     0, 0, 0, 1, 0, 0);
  for (int p = 0; p < NPH; ++p) {
    int q = p & 1;
    int np1 = (p + 1 < NPH) ? (p + 1) : -1;
    int nblk = 256 + ((np1 >= 0) ? 512 : 0);
    hipLaunchKernelGGL(k12, dim3(nblk), dim3(512), 0, stream,
                       wq, pf[q], pb[q], pf[q ^ 1], pb[q ^ 1], x,
                       WihF, bihF, bhhF, WihB, bihB, bhhB,
                       hbuf, hx2, hlast, cstate, stats,
                       256, p * CHUNK, (NPH - 1 - p) * CHUNK,
                       p == 0 ? 1 : 0, p * CHUNK, np1);
  }
  hipLaunchKernelGGL(k3_prep, dim3(1), dim3(512), 0, stream,
                     stats, gamma, beta, Wlin, blin, w2, b2);
  hipLaunchKernelGGL(k4_post, dim3(8192), dim3(256), 0, stream,
                     hbuf, w2, b2, u, e, post, samp);
  hipLaunchKernelGGL(k5_median, dim3(16), dim3(256), 0, stream, samp, mask);
}

// Round 7
// 3049.485 us; speedup vs baseline: 1.5034x; 1.0964x over previous
//
#include <hip/hip_runtime.h>
#include <math.h>

#define H    256
#define G4H  1024
#define CIN  512
#define BB   16
#define TT   2048
#define CHUNK 128
#define NPH  16   // TT/CHUNK

typedef unsigned long long ull;

// ---- workspace layout (in floats) ----
#define OFF_WQ      ((size_t)0)                        // 524288
#define OFF_PF0     ((size_t)524288)                   // 2097152 (proj fwd, parity 0)
#define OFF_PF1     ((size_t)2621440)                  // 2097152 (proj fwd, parity 1)
#define OFF_PB0     ((size_t)4718592)                  // 2097152 (proj bwd, parity 0)
#define OFF_PB1     ((size_t)6815744)                  // 2097152 (proj bwd, parity 1)
#define OFF_HBUF    ((size_t)8912896)                  // 16777216
#define OFF_STATS   ((size_t)25690112)                 // 1024
#define OFF_CSTATE  ((size_t)25691136)                 // 8192
#define OFF_HX      ((size_t)25699328)                 // 16384 ull = 32768 floats
#define OFF_W2      ((size_t)25732096)                 // 1024
#define OFF_B2      ((size_t)25733120)                 // 16
#define OFF_SAMP    ((size_t)25733136)                 // 32768
#define OFF_HLAST   ((size_t)25765904)                 // 8192 (cross-dispatch handoff)

#define REP16(X) X(0) X(1) X(2) X(3) X(4) X(5) X(6) X(7) X(8) X(9) X(10) X(11) \
  X(12) X(13) X(14) X(15)

// fast transcendentals for the LSTM cell (v_exp_f32 / v_rcp_f32 based; verified r1).
__device__ __forceinline__ float frcp_(float x) { return __builtin_amdgcn_rcpf(x); }
__device__ __forceinline__ float fsig_(float x) { return frcp_(1.f + __expf(-x)); }
__device__ __forceinline__ float ftanh_(float x) {
  float a = fabsf(x);
  float e = __expf(-2.f * a);
  float t = (1.f - e) * frcp_(1.f + e);
  return copysignf(t, x);
}

// ---------------- K0: repack Whh; zero stats + hx tag words ----------------
// wq float4 idx = (dir*4+kq)*16384 + q*1024 + gate*256 + s*32 + jl
__global__ __launch_bounds__(256) void k0_init(
    const float* __restrict__ WhhF, const float* __restrict__ WhhB,
    float4* __restrict__ wq, float* __restrict__ stats, int* __restrict__ hxw) {
  int idx = blockIdx.x * 256 + threadIdx.x;
  if (idx < 131072) {
    int jl = idx & 31, s = (idx >> 5) & 7, gate = (idx >> 8) & 3;
    int q = (idx >> 10) & 15, kq = (idx >> 14) & 3, dir = idx >> 16;
    int row = gate * 256 + s * 32 + jl;
    int col = kq * 64 + q * 4;
    const float* W = (dir ? WhhB : WhhF) + (size_t)row * H + col;
    wq[idx] = make_float4(W[0], W[1], W[2], W[3]);
  }
  if (idx < 1024) stats[idx] = 0.f;
  if (idx < 32768) hxw[idx] = 0;   // tags=0 < any target>=1
}

// ---------------- K12: fused recurrence (blocks < nk2) + next-phase proj GEMM ----
// k2 role: 8 sibling WGs x 512 thr per (dir,b); r3's proven tagged agent-atomic
//   exchange (plain relaxed agent store publish). r7 delta: PAIRED polls --
//   112 poller threads each watch 2 adjacent tagged words, both loads in flight
//   per sample iteration -> per-word sampling period unchanged (1 RT), LLC poll
//   request count halved (r6 showed the exchange regresses when traffic rises;
//   this goes the other way). Pairs never straddle the 32-aligned own slice.
//   Own slice via LDS; step-0 handoff via plain hlast (stream-ordered).
// k1 role: 64t x 128g tile per block, 512 thr; writes proj for phase p1 into the
//   parity buffer k2 is NOT reading this dispatch.
__global__ __launch_bounds__(512, 1) void k12(
    const float4* __restrict__ wq,
    const float* __restrict__ pF2, const float* __restrict__ pB2,   // k2 reads
    float* __restrict__ pF1, float* __restrict__ pB1,               // k1 writes
    const float* __restrict__ x,
    const float* __restrict__ WihF, const float* __restrict__ bihF, const float* __restrict__ bhhF,
    const float* __restrict__ WihB, const float* __restrict__ bihB, const float* __restrict__ bhhB,
    float* __restrict__ hbuf, ull* __restrict__ hx2, float* __restrict__ hlast,
    float* __restrict__ cstate, float* __restrict__ stats,
    int nk2, int t0f2, int t0b2, int first, int ebase, int p1) {
  __shared__ __align__(16) float smem[16 * 68 + 16 * 132];  // 3200 floats, role-overlaid

  if ((int)blockIdx.x < nk2) {
    // ================= k2 role: LSTM recurrence =================
    float* h_lds = smem;          // [256]
    float* pbuf  = smem + 256;    // [512]
    const int tid = threadIdx.x;
    const int l = tid & 63, w = tid >> 6;
    const int jl = tid & 31, gate = (tid >> 5) & 3, kq = tid >> 7;
    const int bx = blockIdx.x;
    const int grp = bx & 31, s = bx >> 5;     // 8 siblings: {g, g+32, ..., g+224}
    const int dir = grp >> 4, b = grp & 15;
    const int row = gate * 256 + s * 32 + jl;

    const float4* wbase = wq + (size_t)(dir * 4 + kq) * 16384 + gate * 256 + s * 32 + jl;
#define WDECL(i) float wx##i, wy##i, wz##i, ww##i; \
    { float4 t_ = wbase[(size_t)(i) * 1024]; \
      wx##i = t_.x; wy##i = t_.y; wz##i = t_.z; ww##i = t_.w; } \
    asm volatile("" : "+v"(wx##i), "+v"(wy##i), "+v"(wz##i), "+v"(ww##i));
    REP16(WDECL)
#undef WDECL

    float c = 0.f, s1 = 0.f, s2 = 0.f;
    if (w == 0 && l < 32 && !first) c = cstate[grp * 256 + s * 32 + l];

    const float* pbase = dir ? pB2 : pF2;
    float pv = 0.f;
    if (kq == 0) {
      int tc0 = dir ? (CHUNK - 1) : 0;
      pv = pbase[((size_t)tc0 * BB + b) * G4H + row];
    }

    for (int step = 0; step < CHUNK; ++step) {
      int abs = ebase + step;

      // acquire h_{abs-1}
      if (step == 0) {
        if (tid < 256) h_lds[tid] = (abs == 0) ? 0.f : hlast[grp * 256 + tid];
      } else if (tid < 128) {
        int w0i = 2 * tid;
        if ((w0i >> 5) != s) {                 // own slice already in h_lds
          ull* p0 = hx2 + (size_t)((abs - 1) & 1) * 8192 + grp * 256 + w0i;
          // paired poll: both loads in flight each iteration -> one RT/sample,
          // half the LLC request count vs one-word-per-thread polling.
          ull wa = __hip_atomic_load(p0,     __ATOMIC_RELAXED, __HIP_MEMORY_SCOPE_AGENT);
          ull wb = __hip_atomic_load(p0 + 1, __ATOMIC_RELAXED, __HIP_MEMORY_SCOPE_AGENT);
          while (((int)(wa >> 32) < abs) | ((int)(wb >> 32) < abs)) {
            if ((int)(wa >> 32) < abs)
              wa = __hip_atomic_load(p0,     __ATOMIC_RELAXED, __HIP_MEMORY_SCOPE_AGENT);
            if ((int)(wb >> 32) < abs)
              wb = __hip_atomic_load(p0 + 1, __ATOMIC_RELAXED, __HIP_MEMORY_SCOPE_AGENT);
          }
          *(float2*)(h_lds + w0i) =
              make_float2(__uint_as_float((unsigned)wa), __uint_as_float((unsigned)wb));
        }
      }
      __syncthreads();                          // A: h ready

      float acc = (kq == 0) ? pv : 0.f;
      const float4* h4p = ((const float4*)h_lds) + (kq << 4);
#define WFMA(i) { float4 hv = h4p[i]; \
      acc += wx##i * hv.x + wy##i * hv.y + wz##i * hv.z + ww##i * hv.w; }
      REP16(WFMA)
#undef WFMA
      pbuf[tid] = acc;
      __syncthreads();                          // B: partials ready

      if (w == 0 && l < 32) {
        float gi = pbuf[l]       + pbuf[128 + l] + pbuf[256 + l] + pbuf[384 + l];
        float gf = pbuf[32 + l]  + pbuf[160 + l] + pbuf[288 + l] + pbuf[416 + l];
        float gg = pbuf[64 + l]  + pbuf[192 + l] + pbuf[320 + l] + pbuf[448 + l];
        float go = pbuf[96 + l]  + pbuf[224 + l] + pbuf[352 + l] + pbuf[480 + l];
        float ig = fsig_(gi);
        float fg = fsig_(gf);
        float gz = ftanh_(gg);
        float og = fsig_(go);
        c = fg * c + ig * gz;
        float h = og * ftanh_(c);
        int j = s * 32 + l;
        h_lds[j] = h;                           // own-slice local publish
        ull wd = ((ull)(unsigned)(abs + 1) << 32) | (ull)__float_as_uint(h);
        __hip_atomic_store(hx2 + (size_t)(abs & 1) * 8192 + grp * 256 + j, wd,
                           __ATOMIC_RELAXED, __HIP_MEMORY_SCOPE_AGENT);
        s1 += h; s2 += h * h;
        if (step == CHUNK - 1) hlast[grp * 256 + j] = h;  // next-dispatch handoff
        int tc = dir ? (CHUNK - 1 - step) : step;
        int t = (dir ? t0b2 : t0f2) + tc;
        hbuf[((size_t)t * BB + b) * 512 + dir * 256 + j] = h;
      }
      if (kq == 0 && step + 1 < CHUNK) {        // prefetch next proj
        int tcn = dir ? (CHUNK - 2 - step) : (step + 1);
        pv = pbase[((size_t)tcn * BB + b) * G4H + row];
      }
      // no bottom barrier: next poll + barrier A separates steps
    }

    if (w == 0 && l < 32) {
      cstate[grp * 256 + s * 32 + l] = c;
      atomicAdd(&stats[dir * 256 + s * 32 + l], s1);
      atomicAdd(&stats[512 + dir * 256 + s * 32 + l], s2);
    }
    return;
  }

  // ================= k1 role: proj GEMM for phase p1 =================
  if (p1 < 0) return;
  float* Xs = smem;             // [16][68]
  float* Ws = smem + 16 * 68;   // [16][132]
  int bid = (int)blockIdx.x - nk2;
  int ttile = bid & 1, gtile = (bid >> 1) & 7, zb = bid >> 4;
  int b = zb & 15, dir = zb >> 4;
  const float* Wih = dir ? WihB : WihF;
  const float* bih = dir ? bihB : bihF;
  const float* bhh = dir ? bhhB : bhhF;
  float* proj = dir ? pB1 : pF1;
  int t0 = (dir ? (NPH - 1 - p1) : p1) * CHUNK;
  int tbase = t0 + ttile * 64;
  int gbase = gtile * 128;
  int tid = threadIdx.x;
  int tx = tid & 15, ty = tid >> 4;           // ty 0..31
  float acc[4][4];
#pragma unroll
  for (int i = 0; i < 4; i++)
#pragma unroll
    for (int j = 0; j < 4; j++) acc[i][j] = 0.f;

  int lt = tid & 63, lk = tid >> 6;           // X: 2 rows (lk, lk+8) x 64 t
  int wg = tid >> 2, wc = tid & 3;            // W: 128 g-rows x one float4 of c
  const float* xb = x + (size_t)b * CIN * TT + tbase + lt;
  const float* wp = Wih + (size_t)(gbase + wg) * CIN + 4 * wc;

  float rxa = xb[(size_t)lk * TT];
  float rxb = xb[(size_t)(lk + 8) * TT];
  float4 rw = *(const float4*)wp;

  for (int c0 = 0; c0 < CIN; c0 += 16) {
    __syncthreads();
    Xs[lk * 68 + lt] = rxa;
    Xs[(lk + 8) * 68 + lt] = rxb;
    Ws[(4 * wc + 0) * 132 + wg] = rw.x;
    Ws[(4 * wc + 1) * 132 + wg] = rw.y;
    Ws[(4 * wc + 2) * 132 + wg] = rw.z;
    Ws[(4 * wc + 3) * 132 + wg] = rw.w;
    __syncthreads();
    if (c0 + 16 < CIN) {
      rxa = xb[(size_t)(c0 + 16 + lk) * TT];
      rxb = xb[(size_t)(c0 + 16 + lk + 8) * TT];
      rw  = *(const float4*)(wp + c0 + 16);
    }
#pragma unroll
    for (int kk = 0; kk < 16; kk++) {
      float4 av = *(const float4*)&Xs[kk * 68 + tx * 4];
      float4 bv = *(const float4*)&Ws[kk * 132 + ty * 4];
      acc[0][0] += av.x * bv.x; acc[0][1] += av.x * bv.y; acc[0][2] += av.x * bv.z; acc[0][3] += av.x * bv.w;
      acc[1][0] += av.y * bv.x; acc[1][1] += av.y * bv.y; acc[1][2] += av.y * bv.z; acc[1][3] += av.y * bv.w;
      acc[2][0] += av.z * bv.x; acc[2][1] += av.z * bv.y; acc[2][2] += av.z * bv.z; acc[2][3] += av.z * bv.w;
      acc[3][0] += av.w * bv.x; acc[3][1] += av.w * bv.y; acc[3][2] += av.w * bv.z; acc[3][3] += av.w * bv.w;
    }
  }
  int g0 = gbase + ty * 4;
  float bias0 = bih[g0 + 0] + bhh[g0 + 0];
  float bias1 = bih[g0 + 1] + bhh[g0 + 1];
  float bias2 = bih[g0 + 2] + bhh[g0 + 2];
  float bias3 = bih[g0 + 3] + bhh[g0 + 3];
#pragma unroll
  for (int i = 0; i < 4; i++) {
    int tc = ttile * 64 + tx * 4 + i;
    float4 st = make_float4(acc[i][0] + bias0, acc[i][1] + bias1,
                            acc[i][2] + bias2, acc[i][3] + bias3);
    *(float4*)(proj + ((size_t)tc * BB + b) * G4H + g0) = st;
  }
}

// ---------------- K3: fold BN into linear ----------------
__global__ __launch_bounds__(512) void k3_prep(
    const float* __restrict__ stats, const float* __restrict__ gamma,
    const float* __restrict__ beta, const float* __restrict__ Wlin,
    const float* __restrict__ blin, float* __restrict__ w2, float* __restrict__ b2) {
  __shared__ float r0[512], r1[512];
  int ch = threadIdx.x;
  float mean = stats[ch] * (1.f / 32768.f);
  float var  = stats[512 + ch] * (1.f / 32768.f) - mean * mean;
  float sc = gamma[ch] * rsqrtf(var + 1e-5f);
  float w0 = Wlin[ch], w1 = Wlin[512 + ch];
  w2[ch] = w0 * sc; w2[512 + ch] = w1 * sc;
  float tt = beta[ch] - mean * sc;
  r0[ch] = w0 * tt; r1[ch] = w1 * tt;
  __syncthreads();
  for (int off = 256; off > 0; off >>= 1) {
    if (ch < off) { r0[ch] += r0[ch + off]; r1[ch] += r1[ch + off]; }
    __syncthreads();
  }
  if (ch == 0) { b2[0] = blin[0] + r0[0]; b2[1] = blin[1] + r1[0]; }
}

// ---------------- K4: posterior + gumbel hard sample; one wave per (b,t) ----------------
__global__ __launch_bounds__(256) void k4_post(
    const float* __restrict__ hbuf, const float* __restrict__ w2,
    const float* __restrict__ b2, const float* __restrict__ u,
    const float* __restrict__ e, float* __restrict__ post,
    float* __restrict__ samp) {
  int wid = (blockIdx.x * 256 + threadIdx.x) >> 6;
  int lane = threadIdx.x & 63;
  int b = wid >> 11, t = wid & 2047;
  const float* hr = hbuf + ((size_t)t * BB + b) * 512;
  int c0 = lane * 8;
  float4 h0 = *(const float4*)(hr + c0);
  float4 h1 = *(const float4*)(hr + c0 + 4);
  float4 wa = *(const float4*)(w2 + c0);
  float4 wb = *(const float4*)(w2 + c0 + 4);
  float4 va = *(const float4*)(w2 + 512 + c0);
  float4 vb = *(const float4*)(w2 + 512 + c0 + 4);
  float d0 = h0.x * wa.x + h0.y * wa.y + h0.z * wa.z + h0.w * wa.w
           + h1.x * wb.x + h1.y * wb.y + h1.z * wb.z + h1.w * wb.w;
  float d1 = h0.x * va.x + h0.y * va.y + h0.z * va.z + h0.w * va.w
           + h1.x * vb.x + h1.y * vb.y + h1.z * vb.z + h1.w * vb.w;
#pragma unroll
  for (int off = 32; off > 0; off >>= 1) {
    d0 += __shfl_xor(d0, off, 64);
    d1 += __shfl_xor(d1, off, 64);
  }
  if (lane == 0) {
    float z0 = (d0 + b2[0]) * 0.1f, z1 = (d1 + b2[1]) * 0.1f;
    float m = fmaxf(z0, z1);
    float e0 = expf(z0 - m), e1 = expf(z1 - m);
    float inv = 1.f / (e0 + e1);
    float p0 = e0 * inv, p1 = e1 * inv;
    size_t o = (size_t)b * TT + t;
    post[o * 2] = p0; post[o * 2 + 1] = p1;
    float u0 = u[o * 2], u1 = u[o * 2 + 1];
    float g0 = -logf(-logf(u0 + 1e-20f) + 1e-20f);
    float g1 = -logf(-logf(u1 + 1e-20f) + 1e-20f);
    float a0 = logf(p0) + g0, a1 = logf(p1) + g1;
    samp[o] = (a1 > a0) ? e[o] : 0.f;  // strict >: np.argmax tie -> class 0
  }
}

// ---------------- K5: 3x median-of-5 (reflect pad), one WG per b ----------------
#define MSWAP(a, b) { float lo_ = fminf(a, b); b = fmaxf(a, b); a = lo_; }
__global__ __launch_bounds__(256) void k5_median(
    const float* __restrict__ samp, float* __restrict__ mask) {
  __shared__ float buf[2][TT];
  int b = blockIdx.x, tid = threadIdx.x;
  for (int i = tid; i < TT; i += 256) buf[0][i] = samp[(size_t)b * TT + i];
  __syncthreads();
  int src = 0;
  for (int pass = 0; pass < 3; ++pass) {
    for (int i = tid; i < TT; i += 256) {
      float v0, v1, v2, v3, v4;
      {
        int i0 = i - 2; i0 = i0 < 0 ? -i0 : i0;
        int i1 = i - 1; i1 = i1 < 0 ? -i1 : i1;
        int i3 = i + 1; i3 = i3 > TT - 1 ? 2 * (TT - 1) - i3 : i3;
        int i4 = i + 2; i4 = i4 > TT - 1 ? 2 * (TT - 1) - i4 : i4;
        v0 = buf[src][i0]; v1 = buf[src][i1]; v2 = buf[src][i];
        v3 = buf[src][i3]; v4 = buf[src][i4];
      }
      MSWAP(v0, v1); MSWAP(v3, v4); MSWAP(v2, v4); MSWAP(v2, v3);
      MSWAP(v1, v4); MSWAP(v0, v3); MSWAP(v0, v2); MSWAP(v1, v3);
      MSWAP(v1, v2);
      buf[1 - src][i] = v2;
    }
    __syncthreads();
    src = 1 - src;
  }
  for (int i = tid; i < TT; i += 256) mask[(size_t)b * TT + i] = buf[src][i];
}

extern "C" void kernel_launch(void* const* d_in, const int* in_sizes, int n_in,
                              void* d_out, int out_size, void* d_ws, size_t ws_size,
                              hipStream_t stream) {
  const float* x    = (const float*)d_in[0];
  const float* e    = (const float*)d_in[1];
  const float* u    = (const float*)d_in[2];
  const float* WihF = (const float*)d_in[3];
  const float* WhhF = (const float*)d_in[4];
  const float* bihF = (const float*)d_in[5];
  const float* bhhF = (const float*)d_in[6];
  const float* WihB = (const float*)d_in[7];
  const float* WhhB = (const float*)d_in[8];
  const float* bihB = (const float*)d_in[9];
  const float* bhhB = (const float*)d_in[10];
  const float* gamma= (const float*)d_in[11];
  const float* beta = (const float*)d_in[12];
  const float* Wlin = (const float*)d_in[13];
  const float* blin = (const float*)d_in[14];

  float* ws = (float*)d_ws;
  float4* wq    = (float4*)(ws + OFF_WQ);
  float* pf[2]  = { ws + OFF_PF0, ws + OFF_PF1 };
  float* pb[2]  = { ws + OFF_PB0, ws + OFF_PB1 };
  float* hbuf   = ws + OFF_HBUF;
  float* stats  = ws + OFF_STATS;
  float* cstate = ws + OFF_CSTATE;
  ull*   hx2    = (ull*)(ws + OFF_HX);
  float* w2     = ws + OFF_W2;
  float* b2     = ws + OFF_B2;
  float* samp   = ws + OFF_SAMP;
  float* hlast  = ws + OFF_HLAST;

  float* post = (float*)d_out;
  float* mask = (float*)d_out + (size_t)BB * TT * 2;

  hipLaunchKernelGGL(k0_init, dim3(512), dim3(256), 0, stream,
                     WhhF, WhhB, wq, stats, (int*)hx2);
  // prologue: proj for phase 0 into parity-0 buffers (k1 role only)
  hipLaunchKernelGGL(k12, dim3(512), dim3(512), 0, stream,
                     wq, pf[0], pb[0], pf[0], pb[0], x,
                     WihF, bihF, bhhF, WihB, bihB, bhhB,
                     hbuf, hx2, hlast, cstate, stats,
                     0, 0, 0, 1, 0, 0);
  for (int p = 0; p < NPH; ++p) {
    int q = p & 1;
    int np1 = (p + 1 < NPH) ? (p + 1) : -1;
    int nblk = 256 + ((np1 >= 0) ? 512 : 0);
    hipLaunchKernelGGL(k12, dim3(nblk), dim3(512), 0, stream,
                       wq, pf[q], pb[q], pf[q ^ 1], pb[q ^ 1], x,
                       WihF, bihF, bhhF, WihB, bihB, bhhB,
                       hbuf, hx2, hlast, cstate, stats,
                       256, p * CHUNK, (NPH - 1 - p) * CHUNK,
                       p == 0 ? 1 : 0, p * CHUNK, np1);
  }
  hipLaunchKernelGGL(k3_prep, dim3(1), dim3(512), 0, stream,
                     stats, gamma, beta, Wlin, blin, w2, b2);
  hipLaunchKernelGGL(k4_post, dim3(8192), dim3(256), 0, stream,
                     hbuf, w2, b2, u, e, post, samp);
  hipLaunchKernelGGL(k5_median, dim3(16), dim3(256), 0, stream, samp, mask);
}